// Round 1
// baseline (6677.790 us; speedup 1.0000x reference)
//
#include <hip/hip_runtime.h>
#include <hip/hip_fp16.h>

// LSTM: B=256, T=1024, D=128, H=256.
// Phase 1: Gx[b,t,g] = x[b,t,:] @ Wg[:, :128]^T + bias_g   (f16, MFMA, fragment-permuted layout)
// Phase 2: persistent recurrence, 16 wgs x 16 rows, Wh resident in VGPR+LDS as f16 MFMA B-frags.
// Phase 3: out[b] = sigmoid([hid, cov] @ W2^T + b2)

typedef _Float16 half8 __attribute__((ext_vector_type(8)));
typedef float f32x4 __attribute__((ext_vector_type(4)));

#define MFMA16(a, b, c) __builtin_amdgcn_mfma_f32_16x16x32_f16((a), (b), (c), 0, 0, 0)

__device__ __forceinline__ float sigf(float x) {
  x = fminf(fmaxf(x, -30.f), 30.f);
  return 1.f / (1.f + __expf(-x));
}
__device__ __forceinline__ float tanhf_fast(float x) {
  x = fminf(fmaxf(x, -15.f), 15.f);
  float e = __expf(2.f * x);
  return (e - 1.f) / (e + 1.f);
}
__device__ __forceinline__ float2 h2f2(unsigned int u) {
  __half2 h;
  __builtin_memcpy(&h, &u, 4);
  return __half22float2(h);
}

// ---------------------------------------------------------------------------
// Phase 1: x-part GEMM. grid = (TC/8, 16 bg, 2 ghalf), block = 256 (4 waves).
// Each wg: M = 8 timesteps x 16 rows (one bg), N = 512 gates (one half).
// W x-part staged in LDS as f16 with 16B-chunk XOR swizzle.
// Output layout (halves): [tl][bg][w2 4][n2 16][lane 64][reg 4]
//   where w2=(g>>6)&3, n2=(g>>8)*4+((g>>4)&3): matches phase-2 acc fragments.
// ---------------------------------------------------------------------------
__global__ __launch_bounds__(256, 2) void gx_kernel(
    const float* __restrict__ Wi, const float* __restrict__ bi,
    const float* __restrict__ Wf, const float* __restrict__ bf,
    const float* __restrict__ Wo, const float* __restrict__ bo,
    const float* __restrict__ Wc, const float* __restrict__ bc,
    const float* __restrict__ x, __half* __restrict__ gx, int t0)
{
  __shared__ __half wlds[512 * 128];  // 128 KB
  const int tid = threadIdx.x;
  const int l = tid & 63, wv = tid >> 6;
  const int kq = l >> 4, col = l & 15;
  const int tch = blockIdx.x, bg = blockIdx.y, gh = blockIdx.z;

  // ---- stage W x-part (gates gh*512..+512, cols 0..127) into LDS f16 ----
  for (int rr = 0; rr < 2; ++rr) {
    int gl = tid * 2 + rr;              // 0..511 local gate row
    int gg = gh * 512 + gl;             // global gate row
    int q = gg >> 8;
    const float* Wq = (q == 0) ? Wi : (q == 1) ? Wf : (q == 2) ? Wo : Wc;
    const float* src = Wq + (size_t)(gg & 255) * 384;  // x-part = cols [0,128)
    char* dst_row = (char*)wlds + gl * 256;
#pragma unroll
    for (int c = 0; c < 16; ++c) {
      float4 a = *(const float4*)(src + c * 8);
      float4 b = *(const float4*)(src + c * 8 + 4);
      half8 h = {(_Float16)a.x, (_Float16)a.y, (_Float16)a.z, (_Float16)a.w,
                 (_Float16)b.x, (_Float16)b.y, (_Float16)b.z, (_Float16)b.w};
      *(half8*)(dst_row + ((c ^ (gl & 15)) * 16)) = h;  // XOR swizzle, bijective in-row
    }
  }
  __syncthreads();

  // ---- A fragments: 8 timesteps x 4 k-tiles (x rows, f32 -> f16) ----
  half8 afr[8][4];
  const size_t brow = (size_t)(bg * 16 + col);
#pragma unroll
  for (int m = 0; m < 8; ++m) {
    int tt = t0 + tch * 8 + m;
    const float* xp = x + (brow * 1024 + tt) * 128 + kq * 8;
#pragma unroll
    for (int k = 0; k < 4; ++k) {
      float4 a = *(const float4*)(xp + k * 32);
      float4 b = *(const float4*)(xp + k * 32 + 4);
      afr[m][k] = {(_Float16)a.x, (_Float16)a.y, (_Float16)a.z, (_Float16)a.w,
                   (_Float16)b.x, (_Float16)b.y, (_Float16)b.z, (_Float16)b.w};
    }
  }

  // ---- per wave: 8 n-tiles of 16 gates ----
#pragma unroll
  for (int n = 0; n < 8; ++n) {
    int gbase = gh * 512 + wv * 128 + n * 16;
    int gcol = gbase + col;
    int q = gcol >> 8;  // never crosses within a 16-tile
    const float* Bq = (q == 0) ? bi : (q == 1) ? bf : (q == 2) ? bo : bc;
    float bv = Bq[gcol & 255];
    int glb = wv * 128 + n * 16 + col;  // local row in wlds
    half8 wf[4];
#pragma unroll
    for (int k = 0; k < 4; ++k)
      wf[k] = *(const half8*)((char*)wlds + glb * 256 + (((k * 4 + kq) ^ (glb & 15)) * 16));
    int w2 = (gbase >> 6) & 3;
    int n2 = (gbase >> 8) * 4 + ((gbase >> 4) & 3);
#pragma unroll
    for (int m = 0; m < 8; ++m) {
      f32x4 acc = {bv, bv, bv, bv};
#pragma unroll
      for (int k = 0; k < 4; ++k) acc = MFMA16(afr[m][k], wf[k], acc);
      int tl = tch * 8 + m;
      size_t idx = ((((size_t)tl * 16 + bg) * 4 + w2) * 16 + n2) * 256 + l * 4;
      unsigned int lo = (unsigned int)__half_as_ushort(__float2half_rn(acc[0])) |
                        ((unsigned int)__half_as_ushort(__float2half_rn(acc[1])) << 16);
      unsigned int hi = (unsigned int)__half_as_ushort(__float2half_rn(acc[2])) |
                        ((unsigned int)__half_as_ushort(__float2half_rn(acc[3])) << 16);
      uint2 v = {lo, hi};
      *(uint2*)(gx + idx) = v;
    }
  }
}

// ---------------------------------------------------------------------------
// Phase 2: persistent recurrence. grid = 16 (bg), block = 256 (4 waves, 1/SIMD).
// Wave w owns hidden slice j in [w*64, w*64+64) for all 4 gates (16 n-tiles).
// Wh frags: n<11 all k, plus (n==11,k<2) in VGPRs (90 frags = 360 VGPR);
//           remaining 38 frags/wave in LDS (152 KB). h-frag exchange: 8 KB LDS.
// ---------------------------------------------------------------------------
#define GETW(n, k)                                                            \
  (((n) < 11 || ((n) == 11 && (k) < 2))                                       \
       ? wfr[(n) * 8 + (k)]                                                   \
       : *(const half8*)(WL + (((n) - 11) * 8 + (k) - 2) * 1024 + l * 16))

__global__ __launch_bounds__(256, 1) void rec_kernel(
    const float* __restrict__ Wi, const float* __restrict__ Wf,
    const float* __restrict__ Wo, const float* __restrict__ Wc,
    const __half* __restrict__ gx, float* __restrict__ dout,
    float* __restrict__ c_plain, float* __restrict__ c_state,
    float* __restrict__ h_state, int t0, int tc)
{
  __shared__ char lds[163840];  // 152 KB W frags + 8 KB h frags = 160 KB
  const int tid = threadIdx.x;
  const int l = tid & 63, w = tid >> 6;
  const int kq = l >> 4, col = l & 15;
  const int bg = blockIdx.x;
  char* WL = lds + w * 38 * 1024;
  char* HF = lds + 155648;

  // ---- load resident Wh fragments (h-part cols [128,384)) ----
  half8 wfr[90];
#pragma unroll
  for (int n = 0; n < 16; ++n) {
    const int q = n >> 2;
    const float* Wq = (q == 0) ? Wi : (q == 1) ? Wf : (q == 2) ? Wo : Wc;
    int j = w * 64 + (n & 3) * 16 + col;
    const float* src = Wq + (size_t)j * 384 + 128 + kq * 8;
#pragma unroll
    for (int k = 0; k < 8; ++k) {
      float4 a = *(const float4*)(src + k * 32);
      float4 b = *(const float4*)(src + k * 32 + 4);
      half8 h = {(_Float16)a.x, (_Float16)a.y, (_Float16)a.z, (_Float16)a.w,
                 (_Float16)b.x, (_Float16)b.y, (_Float16)b.z, (_Float16)b.w};
      if (n < 11 || (n == 11 && k < 2))
        wfr[n * 8 + k] = h;
      else
        *(half8*)(WL + ((n - 11) * 8 + k - 2) * 1024 + l * 16) = h;
    }
  }

  // ---- state init / restore ----
  float cst[16];
  if (t0 == 0) {
#pragma unroll
    for (int i = 0; i < 16; ++i) cst[i] = 0.f;
    uint4 z = {0, 0, 0, 0};
    *(uint4*)(HF + tid * 32) = z;
    *(uint4*)(HF + tid * 32 + 16) = z;
  } else {
#pragma unroll
    for (int i = 0; i < 16; ++i) cst[i] = c_state[(size_t)(bg * 256 + tid) * 16 + i];
    const uint4* hs = (const uint4*)((const char*)h_state + bg * 8192);
    *(uint4*)(HF + tid * 32) = hs[tid * 2];
    *(uint4*)(HF + tid * 32 + 16) = hs[tid * 2 + 1];
  }

  // ---- Gx prefetch (tile n at +n*512 B, step tt at +tt*524288 B) ----
  const char* gxb_base = (const char*)gx + (size_t)bg * 32768 + w * 8192 + l * 8;
  uint2 gxb[16];
#pragma unroll
  for (int n = 0; n < 16; ++n) gxb[n] = *(const uint2*)(gxb_base + n * 512);

  for (int tt = 0; tt < tc; ++tt) {
    __syncthreads();  // bar1: prev-step h writes visible
    half8 afr[8];
#pragma unroll
    for (int k = 0; k < 8; ++k) afr[k] = *(const half8*)(HF + k * 1024 + l * 16);
    __syncthreads();  // bar2: all reads done before this step's writes
    const bool last = (t0 + tt == 1023);
    const bool pf = (tt + 1 < tc);
    const char* gnext = gxb_base + (size_t)(tt + 1) * 524288;
#pragma unroll
    for (int m = 0; m < 4; ++m) {
      f32x4 ai, afv, ao, ac;
      { float2 p0 = h2f2(gxb[m].x),      p1 = h2f2(gxb[m].y);      ai  = {p0.x, p0.y, p1.x, p1.y}; }
      { float2 p0 = h2f2(gxb[4 + m].x),  p1 = h2f2(gxb[4 + m].y);  afv = {p0.x, p0.y, p1.x, p1.y}; }
      { float2 p0 = h2f2(gxb[8 + m].x),  p1 = h2f2(gxb[8 + m].y);  ao  = {p0.x, p0.y, p1.x, p1.y}; }
      { float2 p0 = h2f2(gxb[12 + m].x), p1 = h2f2(gxb[12 + m].y); ac  = {p0.x, p0.y, p1.x, p1.y}; }
#pragma unroll
      for (int k = 0; k < 8; ++k) ai  = MFMA16(afr[k], GETW(m, k),      ai);
#pragma unroll
      for (int k = 0; k < 8; ++k) afv = MFMA16(afr[k], GETW(4 + m, k),  afv);
#pragma unroll
      for (int k = 0; k < 8; ++k) ao  = MFMA16(afr[k], GETW(8 + m, k),  ao);
#pragma unroll
      for (int k = 0; k < 8; ++k) ac  = MFMA16(afr[k], GETW(12 + m, k), ac);
      // h-frag write base for this m (j = w*64 + m*16 + col, row = kq*4 + rg)
      char* hwp = HF + (w * 2 + (m >> 1)) * 1024 + ((m & 1) * 2 + (col >> 3)) * 256 +
                  kq * 64 + (l & 7) * 2;
#pragma unroll
      for (int rg = 0; rg < 4; ++rg) {
        float ig = sigf(ai[rg]), fg = sigf(afv[rg]), og = sigf(ao[rg]);
        float ct = tanhf_fast(ac[rg]);
        float cv = fg * cst[m * 4 + rg] + ig * ct;
        cst[m * 4 + rg] = cv;
        float hv = og * tanhf_fast(cv);
        *(_Float16*)(hwp + rg * 16) = (_Float16)hv;
        if (last) {
          int j = w * 64 + m * 16 + col;
          int rrow = bg * 16 + kq * 4 + rg;
          dout[256 + (size_t)rrow * 256 + j] = hv;
          c_plain[(size_t)rrow * 256 + j] = cv;
        }
      }
      if (pf) {  // prefetch next step's tiles for this m-group (latency hidden)
        gxb[m]      = *(const uint2*)(gnext + m * 512);
        gxb[4 + m]  = *(const uint2*)(gnext + (4 + m) * 512);
        gxb[8 + m]  = *(const uint2*)(gnext + (8 + m) * 512);
        gxb[12 + m] = *(const uint2*)(gnext + (12 + m) * 512);
      }
    }
  }
  __syncthreads();
  // ---- save chunk state ----
#pragma unroll
  for (int i = 0; i < 16; ++i) c_state[(size_t)(bg * 256 + tid) * 16 + i] = cst[i];
  uint4* hs = (uint4*)((char*)h_state + bg * 8192);
  hs[tid * 2]     = *(const uint4*)(HF + tid * 32);
  hs[tid * 2 + 1] = *(const uint4*)(HF + tid * 32 + 16);
}

// ---------------------------------------------------------------------------
// Phase 3: out[b] = sigmoid(hid[b,:].W2[:256] + cov[b,:].W2[256:] + b2)
// ---------------------------------------------------------------------------
__global__ void head_kernel(const float* __restrict__ hid, const float* __restrict__ cpl,
                            const float* __restrict__ W2, const float* __restrict__ b2,
                            float* __restrict__ out)
{
  int b = blockIdx.x, l = threadIdx.x;  // 64 threads
  float4 hv = ((const float4*)(hid + (size_t)b * 256))[l];
  float4 wv = ((const float4*)W2)[l];
  float s = hv.x * wv.x + hv.y * wv.y + hv.z * wv.z + hv.w * wv.w;
  float4 cv = ((const float4*)(cpl + (size_t)b * 256))[l];
  float4 wc = ((const float4*)(W2 + 256))[l];
  s += cv.x * wc.x + cv.y * wc.y + cv.z * wc.z + cv.w * wc.w;
#pragma unroll
  for (int off = 32; off > 0; off >>= 1) s += __shfl_down(s, off, 64);
  if (l == 0) out[b] = 1.f / (1.f + __expf(-(s + b2[0])));
}

// ---------------------------------------------------------------------------
extern "C" void kernel_launch(void* const* d_in, const int* in_sizes, int n_in,
                              void* d_out, int out_size, void* d_ws, size_t ws_size,
                              hipStream_t stream)
{
  const float* x  = (const float*)d_in[0];
  const float* Wi = (const float*)d_in[1];
  const float* bi = (const float*)d_in[2];
  const float* Wf = (const float*)d_in[3];
  const float* bf = (const float*)d_in[4];
  const float* Wo = (const float*)d_in[5];
  const float* bo = (const float*)d_in[6];
  const float* Wc = (const float*)d_in[7];
  const float* bc = (const float*)d_in[8];
  const float* W2 = (const float*)d_in[9];
  const float* b2 = (const float*)d_in[10];
  float* out = (float*)d_out;

  // ws layout: [gx: TC*512KB][c_plain 256KB][c_state 256KB][h_state 128KB]
  char* ws = (char*)d_ws;
  const size_t state_bytes = (size_t)640 * 1024;
  size_t avail = ws_size > state_bytes ? ws_size - state_bytes : 0;
  size_t tcap = avail / 524288;
  int TC = (int)(tcap > 1024 ? 1024 : (tcap & ~(size_t)7));
  if (TC < 8) TC = 8;  // requires ws_size >= ~5 MB
  __half* gxb = (__half*)ws;
  float* c_plain = (float*)(ws + (size_t)TC * 524288);
  float* c_state = c_plain + 65536;
  float* h_state = c_state + 65536;

  for (int t0 = 0; t0 < 1024; t0 += TC) {
    int tcn = (1024 - t0 < TC) ? (1024 - t0) : TC;
    gx_kernel<<<dim3(tcn / 8, 16, 2), 256, 0, stream>>>(Wi, bi, Wf, bf, Wo, bo, Wc, bc,
                                                        x, gxb, t0);
    rec_kernel<<<16, 256, 0, stream>>>(Wi, Wf, Wo, Wc, gxb, out, c_plain, c_state,
                                       h_state, t0, tcn);
  }
  head_kernel<<<256, 64, 0, stream>>>(out + 256, c_plain, W2, b2, out);
}

// Round 2
// 5424.847 us; speedup vs baseline: 1.2310x; 1.2310x over previous
//
#include <hip/hip_runtime.h>
#include <hip/hip_fp16.h>

// LSTM: B=256, T=1024, D=128, H=256.
// Phase 1: Gx[b,t,g] = x[b,t,:] @ Wg[:, :128]^T + bias_g   (f16, MFMA, fragment-permuted layout)
// Phase 2: persistent recurrence, 16 wgs x 512 thr (8 waves, 2/SIMD).
//          Wave w owns H-slice [w*32, w*32+32) x 4 gates = 8 n-tiles.
//          Wh frags: 45/wave in VGPR (180 regs), 19/wave in LDS (152 KB); h exchange 8 KB.
// Phase 3: out[b] = sigmoid([hid, cov] @ W2^T + b2)

typedef _Float16 half8 __attribute__((ext_vector_type(8)));
typedef float f32x4 __attribute__((ext_vector_type(4)));

#define MFMA16(a, b, c) __builtin_amdgcn_mfma_f32_16x16x32_f16((a), (b), (c), 0, 0, 0)

__device__ __forceinline__ float sigf(float x) {
  x = fminf(fmaxf(x, -30.f), 30.f);
  return __builtin_amdgcn_rcpf(1.f + __expf(-x));
}
__device__ __forceinline__ float2 h2f2(unsigned int u) {
  __half2 h;
  __builtin_memcpy(&h, &u, 4);
  return __half22float2(h);
}

// ---------------------------------------------------------------------------
// Phase 1: x-part GEMM (unchanged from R1, verified). grid=(TC/8,16,2), 256 thr.
// Output layout (halves): [tl][bg][w2 4][n2 16][lane 64][reg 4],
//   w2=(g>>6)&3, n2=(g>>8)*4+((g>>4)&3), g = gate*256 + col.
// ---------------------------------------------------------------------------
__global__ __launch_bounds__(256, 2) void gx_kernel(
    const float* __restrict__ Wi, const float* __restrict__ bi,
    const float* __restrict__ Wf, const float* __restrict__ bf,
    const float* __restrict__ Wo, const float* __restrict__ bo,
    const float* __restrict__ Wc, const float* __restrict__ bc,
    const float* __restrict__ x, __half* __restrict__ gx, int t0)
{
  __shared__ __half wlds[512 * 128];  // 128 KB
  const int tid = threadIdx.x;
  const int l = tid & 63, wv = tid >> 6;
  const int kq = l >> 4, col = l & 15;
  const int tch = blockIdx.x, bg = blockIdx.y, gh = blockIdx.z;

  for (int rr = 0; rr < 2; ++rr) {
    int gl = tid * 2 + rr;
    int gg = gh * 512 + gl;
    int q = gg >> 8;
    const float* Wq = (q == 0) ? Wi : (q == 1) ? Wf : (q == 2) ? Wo : Wc;
    const float* src = Wq + (size_t)(gg & 255) * 384;
    char* dst_row = (char*)wlds + gl * 256;
#pragma unroll
    for (int c = 0; c < 16; ++c) {
      float4 a = *(const float4*)(src + c * 8);
      float4 b = *(const float4*)(src + c * 8 + 4);
      half8 h = {(_Float16)a.x, (_Float16)a.y, (_Float16)a.z, (_Float16)a.w,
                 (_Float16)b.x, (_Float16)b.y, (_Float16)b.z, (_Float16)b.w};
      *(half8*)(dst_row + ((c ^ (gl & 15)) * 16)) = h;
    }
  }
  __syncthreads();

  half8 afr[8][4];
  const size_t brow = (size_t)(bg * 16 + col);
#pragma unroll
  for (int m = 0; m < 8; ++m) {
    int tt = t0 + tch * 8 + m;
    const float* xp = x + (brow * 1024 + tt) * 128 + kq * 8;
#pragma unroll
    for (int k = 0; k < 4; ++k) {
      float4 a = *(const float4*)(xp + k * 32);
      float4 b = *(const float4*)(xp + k * 32 + 4);
      afr[m][k] = {(_Float16)a.x, (_Float16)a.y, (_Float16)a.z, (_Float16)a.w,
                   (_Float16)b.x, (_Float16)b.y, (_Float16)b.z, (_Float16)b.w};
    }
  }

#pragma unroll
  for (int n = 0; n < 8; ++n) {
    int gbase = gh * 512 + wv * 128 + n * 16;
    int gcol = gbase + col;
    int q = gcol >> 8;
    const float* Bq = (q == 0) ? bi : (q == 1) ? bf : (q == 2) ? bo : bc;
    float bv = Bq[gcol & 255];
    int glb = wv * 128 + n * 16 + col;
    half8 wf[4];
#pragma unroll
    for (int k = 0; k < 4; ++k)
      wf[k] = *(const half8*)((char*)wlds + glb * 256 + (((k * 4 + kq) ^ (glb & 15)) * 16));
    int w2 = (gbase >> 6) & 3;
    int n2 = (gbase >> 8) * 4 + ((gbase >> 4) & 3);
#pragma unroll
    for (int m = 0; m < 8; ++m) {
      f32x4 acc = {bv, bv, bv, bv};
#pragma unroll
      for (int k = 0; k < 4; ++k) acc = MFMA16(afr[m][k], wf[k], acc);
      int tl = tch * 8 + m;
      size_t idx = ((((size_t)tl * 16 + bg) * 4 + w2) * 16 + n2) * 256 + l * 4;
      unsigned int lo = (unsigned int)__half_as_ushort(__float2half_rn(acc[0])) |
                        ((unsigned int)__half_as_ushort(__float2half_rn(acc[1])) << 16);
      unsigned int hi = (unsigned int)__half_as_ushort(__float2half_rn(acc[2])) |
                        ((unsigned int)__half_as_ushort(__float2half_rn(acc[3])) << 16);
      uint2 v = {lo, hi};
      *(uint2*)(gx + idx) = v;
    }
  }
}

// ---------------------------------------------------------------------------
// Phase 2: persistent recurrence, 512 threads / WG.
// Wh frag linear index i = (ctl*4+q)*8+k, i<45 in VGPR, else LDS.
// ---------------------------------------------------------------------------
#define NFV 45  // VGPR-resident W frags per wave (rest: 64-NFV=19 in LDS)

#define WFRAG(ctl, q, k)                                                      \
  ((((ctl) * 4 + (q)) * 8 + (k)) < NFV                                        \
       ? wfr[(((ctl) * 4 + (q)) * 8 + (k))]                                   \
       : *(const half8*)(WL + ((((ctl) * 4 + (q)) * 8 + (k)) - NFV) * 1024 + lofs))

__global__ __launch_bounds__(512) void rec_kernel(
    const float* __restrict__ Wi, const float* __restrict__ Wf,
    const float* __restrict__ Wo, const float* __restrict__ Wc,
    const __half* __restrict__ gx, float* __restrict__ dout,
    float* __restrict__ c_plain, float* __restrict__ c_state,
    float* __restrict__ h_state, int t0, int tc)
{
  __shared__ char lds[163840];  // 8 waves * 19 KB W frags + 8 KB h frags
  const int tid = threadIdx.x;
  const int l = tid & 63, w = tid >> 6;
  const int kq = l >> 4, col = l & 15;
  const int lofs = l * 16;
  const int bg = blockIdx.x;
  char* WL = lds + w * 19456;
  char* HF = lds + 155648;

  // ---- load resident Wh fragments (h-part cols [128,384)) ----
  half8 wfr[NFV];
#pragma unroll
  for (int ctl = 0; ctl < 2; ++ctl) {
#pragma unroll
    for (int q = 0; q < 4; ++q) {
      const float* Wq = (q == 0) ? Wi : (q == 1) ? Wf : (q == 2) ? Wo : Wc;
      int j = (w * 2 + ctl) * 16 + col;
      const float* src = Wq + (size_t)j * 384 + 128 + kq * 8;
#pragma unroll
      for (int k = 0; k < 8; ++k) {
        float4 a = *(const float4*)(src + k * 32);
        float4 b = *(const float4*)(src + k * 32 + 4);
        half8 h = {(_Float16)a.x, (_Float16)a.y, (_Float16)a.z, (_Float16)a.w,
                   (_Float16)b.x, (_Float16)b.y, (_Float16)b.z, (_Float16)b.w};
        int i = (ctl * 4 + q) * 8 + k;
        if (i < NFV)
          wfr[i] = h;
        else
          *(half8*)(WL + (i - NFV) * 1024 + lofs) = h;
      }
    }
  }

  // ---- state init / restore ----
  float cst[8];
  if (t0 == 0) {
#pragma unroll
    for (int i = 0; i < 8; ++i) cst[i] = 0.f;
    uint4 z = {0, 0, 0, 0};
    *(uint4*)(HF + tid * 16) = z;
  } else {
#pragma unroll
    for (int i = 0; i < 8; ++i) cst[i] = c_state[(size_t)(bg * 512 + tid) * 8 + i];
    ((uint4*)HF)[tid] = ((const uint4*)((const char*)h_state + bg * 8192))[tid];
  }

  // ---- Gx prefetch: tile (q,ctl) at gbase + q*2048 + ctl*512 + tt*524288 ----
  const char* gbase = (const char*)gx + (size_t)bg * 32768 + (w >> 1) * 8192 +
                      (w & 1) * 1024 + l * 8;
  uint2 gA[4], gB[4];
#pragma unroll
  for (int q = 0; q < 4; ++q) {
    gA[q] = *(const uint2*)(gbase + q * 2048);
    gB[q] = *(const uint2*)(gbase + q * 2048 + 512);
  }

  for (int tt = 0; tt < tc; ++tt) {
    __syncthreads();  // bar1: prev-step h writes visible
    half8 afr[8];
#pragma unroll
    for (int k = 0; k < 8; ++k) afr[k] = *(const half8*)(HF + k * 1024 + lofs);
    __syncthreads();  // bar2: all reads done before this step's writes
    const bool last = (t0 + tt == 1023);
    const bool pf = (tt + 1 < tc);
    const char* gn = gbase + (size_t)(tt + 1) * 524288;

#pragma unroll
    for (int ctl = 0; ctl < 2; ++ctl) {
      f32x4 acc[4];
#pragma unroll
      for (int q = 0; q < 4; ++q) {
        uint2 g = ctl ? gB[q] : gA[q];
        float2 p0 = h2f2(g.x), p1 = h2f2(g.y);
        acc[q] = {p0.x, p0.y, p1.x, p1.y};
      }
      if (pf) {  // refill this ctl-group for step tt+1 (latency hides under MFMA)
#pragma unroll
        for (int q = 0; q < 4; ++q) {
          uint2 v = *(const uint2*)(gn + q * 2048 + ctl * 512);
          if (ctl) gB[q] = v; else gA[q] = v;
        }
      }
#pragma unroll
      for (int k = 0; k < 8; ++k) {
        acc[0] = MFMA16(afr[k], WFRAG(ctl, 0, k), acc[0]);
        acc[1] = MFMA16(afr[k], WFRAG(ctl, 1, k), acc[1]);
        acc[2] = MFMA16(afr[k], WFRAG(ctl, 2, k), acc[2]);
        acc[3] = MFMA16(afr[k], WFRAG(ctl, 3, k), acc[3]);
      }
      // ---- activations + h-frag write ----
      char* hwp = HF + w * 1024 + ctl * 512 + ((l >> 3) & 1) * 256 + kq * 64 + (l & 7) * 2;
#pragma unroll
      for (int rg = 0; rg < 4; ++rg) {
        float a_i = acc[0][rg], a_f = acc[1][rg], a_o = acc[2][rg], a_c = acc[3][rg];
        // i*tanh(c~) = (eC-1) / ((1+eA)(eC+1)),  eA=e^-ai, eC=e^{2ac}
        float eA = __expf(-fminf(fmaxf(a_i, -40.f), 40.f));
        float eC = __expf(2.f * fminf(fmaxf(a_c, -15.f), 15.f));
        float ict = (eC - 1.f) * __builtin_amdgcn_rcpf((1.f + eA) * (eC + 1.f));
        float fg = sigf(a_f);
        float cv = fg * cst[ctl * 4 + rg] + ict;
        cst[ctl * 4 + rg] = cv;
        // o*tanh(cv) = (eV-1) / ((1+eO)(eV+1))
        float eO = __expf(-fminf(fmaxf(a_o, -40.f), 40.f));
        float eV = __expf(2.f * fminf(fmaxf(cv, -15.f), 15.f));
        float hv = (eV - 1.f) * __builtin_amdgcn_rcpf((1.f + eO) * (eV + 1.f));
        *(_Float16*)(hwp + rg * 16) = (_Float16)hv;
        if (last) {
          int j = w * 32 + ctl * 16 + col;
          int rrow = bg * 16 + kq * 4 + rg;
          dout[256 + (size_t)rrow * 256 + j] = hv;
          c_plain[(size_t)rrow * 256 + j] = cv;
        }
      }
    }
  }
  __syncthreads();
  // ---- save chunk state ----
#pragma unroll
  for (int i = 0; i < 8; ++i) c_state[(size_t)(bg * 512 + tid) * 8 + i] = cst[i];
  ((uint4*)((char*)h_state + bg * 8192))[tid] = ((const uint4*)HF)[tid];
}

// ---------------------------------------------------------------------------
// Phase 3: out[b] = sigmoid(hid[b,:].W2[:256] + cov[b,:].W2[256:] + b2)
// ---------------------------------------------------------------------------
__global__ void head_kernel(const float* __restrict__ hid, const float* __restrict__ cpl,
                            const float* __restrict__ W2, const float* __restrict__ b2,
                            float* __restrict__ out)
{
  int b = blockIdx.x, l = threadIdx.x;  // 64 threads
  float4 hv = ((const float4*)(hid + (size_t)b * 256))[l];
  float4 wv = ((const float4*)W2)[l];
  float s = hv.x * wv.x + hv.y * wv.y + hv.z * wv.z + hv.w * wv.w;
  float4 cv = ((const float4*)(cpl + (size_t)b * 256))[l];
  float4 wc = ((const float4*)(W2 + 256))[l];
  s += cv.x * wc.x + cv.y * wc.y + cv.z * wc.z + cv.w * wc.w;
#pragma unroll
  for (int off = 32; off > 0; off >>= 1) s += __shfl_down(s, off, 64);
  if (l == 0) out[b] = 1.f / (1.f + __expf(-(s + b2[0])));
}

// ---------------------------------------------------------------------------
extern "C" void kernel_launch(void* const* d_in, const int* in_sizes, int n_in,
                              void* d_out, int out_size, void* d_ws, size_t ws_size,
                              hipStream_t stream)
{
  const float* x  = (const float*)d_in[0];
  const float* Wi = (const float*)d_in[1];
  const float* bi = (const float*)d_in[2];
  const float* Wf = (const float*)d_in[3];
  const float* bf = (const float*)d_in[4];
  const float* Wo = (const float*)d_in[5];
  const float* bo = (const float*)d_in[6];
  const float* Wc = (const float*)d_in[7];
  const float* bc = (const float*)d_in[8];
  const float* W2 = (const float*)d_in[9];
  const float* b2 = (const float*)d_in[10];
  float* out = (float*)d_out;

  // ws layout: [gx: TC*512KB][c_plain 256KB][c_state 256KB][h_state 128KB]
  char* ws = (char*)d_ws;
  const size_t state_bytes = (size_t)640 * 1024;
  size_t avail = ws_size > state_bytes ? ws_size - state_bytes : 0;
  size_t tcap = avail / 524288;
  int TC = (int)(tcap > 1024 ? 1024 : (tcap & ~(size_t)7));
  if (TC < 8) TC = 8;  // requires ws_size >= ~5 MB
  __half* gxb = (__half*)ws;
  float* c_plain = (float*)(ws + (size_t)TC * 524288);
  float* c_state = c_plain + 65536;
  float* h_state = c_state + 65536;

  for (int t0 = 0; t0 < 1024; t0 += TC) {
    int tcn = (1024 - t0 < TC) ? (1024 - t0) : TC;
    gx_kernel<<<dim3(tcn / 8, 16, 2), 256, 0, stream>>>(Wi, bi, Wf, bf, Wo, bo, Wc, bc,
                                                        x, gxb, t0);
    rec_kernel<<<16, 512, 0, stream>>>(Wi, Wf, Wo, Wc, gxb, out, c_plain, c_state,
                                       h_state, t0, tcn);
  }
  head_kernel<<<256, 64, 0, stream>>>(out + 256, c_plain, W2, b2, out);
}

// Round 3
// 4623.385 us; speedup vs baseline: 1.4444x; 1.1733x over previous
//
#include <hip/hip_runtime.h>
#include <hip/hip_fp16.h>

// LSTM: B=256, T=1024, D=128, H=256.
// w16_kernel: W x-part (4x[256,384] f32, cols 0..127) -> w16x [1024][128] f16, once.
// gx_kernel : Gx[b,t,g] = x[b,t,:] @ W[:, :128]^T + bias (f16, MFMA, frag-permuted, no LDS).
// rec_kernel: persistent recurrence, 16 wgs x 512 thr, 2 waves/SIMD, 256-VGPR cap.
//             Wh frags: 46/wave in VGPR (184 regs), 18/wave in LDS (144 KB);
//             h exchange double-buffered (16 KB). One barrier per step.
// head_kernel: out[b] = sigmoid([hid, cov] @ W2^T + b2).

typedef _Float16 half8 __attribute__((ext_vector_type(8)));
typedef float f32x4 __attribute__((ext_vector_type(4)));

#define MFMA16(a, b, c) __builtin_amdgcn_mfma_f32_16x16x32_f16((a), (b), (c), 0, 0, 0)

__device__ __forceinline__ float sigf(float x) {
  x = fminf(fmaxf(x, -30.f), 30.f);
  return __builtin_amdgcn_rcpf(1.f + __expf(-x));
}
__device__ __forceinline__ float2 h2f2(unsigned int u) {
  __half2 h;
  __builtin_memcpy(&h, &u, 4);
  return __half22float2(h);
}

// ---------------------------------------------------------------------------
// W x-part -> f16, rows g = q*256 + r, cols 0..127.
// ---------------------------------------------------------------------------
__global__ void w16_kernel(const float* __restrict__ Wi, const float* __restrict__ Wf,
                           const float* __restrict__ Wo, const float* __restrict__ Wc,
                           __half* __restrict__ w16x)
{
  int g = blockIdx.x, c = threadIdx.x;  // 1024 blocks x 128 threads
  int q = g >> 8;
  const float* Wq = (q == 0) ? Wi : (q == 1) ? Wf : (q == 2) ? Wo : Wc;
  w16x[g * 128 + c] = __float2half_rn(Wq[(size_t)(g & 255) * 384 + c]);
}

// ---------------------------------------------------------------------------
// Phase 1: x-part GEMM, no LDS. grid=(TC/8, 16, 2), 256 thr (4 waves).
// Wave wv owns gates [gh*512 + wv*128, +128) = 8 n-tiles; B-frags from w16x (LLC).
// Output layout: [tl][bg][w2 4][n2 16][lane 64][reg 4], w2=(g>>6)&3,
//   n2=(g>>8)*4+((g>>4)&3), g = gate*256 + col.
// ---------------------------------------------------------------------------
__global__ __launch_bounds__(256) void gx_kernel(
    const __half* __restrict__ w16x,
    const float* __restrict__ bi, const float* __restrict__ bf,
    const float* __restrict__ bo, const float* __restrict__ bc,
    const float* __restrict__ x, __half* __restrict__ gx, int t0)
{
  const int tid = threadIdx.x;
  const int l = tid & 63, wv = tid >> 6;
  const int kq = l >> 4, col = l & 15;
  const int tch = blockIdx.x, bg = blockIdx.y, gh = blockIdx.z;
  const size_t brow = (size_t)(bg * 16 + col);

#pragma unroll
  for (int mh = 0; mh < 2; ++mh) {
    // ---- A fragments: 4 timesteps x 4 k-tiles ----
    half8 afr[4][4];
#pragma unroll
    for (int mm = 0; mm < 4; ++mm) {
      int tt = t0 + tch * 8 + mh * 4 + mm;
      const float* xp = x + (brow * 1024 + tt) * 128 + kq * 8;
#pragma unroll
      for (int k = 0; k < 4; ++k) {
        float4 a = *(const float4*)(xp + k * 32);
        float4 b = *(const float4*)(xp + k * 32 + 4);
        afr[mm][k] = {(_Float16)a.x, (_Float16)a.y, (_Float16)a.z, (_Float16)a.w,
                      (_Float16)b.x, (_Float16)b.y, (_Float16)b.z, (_Float16)b.w};
      }
    }
#pragma unroll
    for (int n = 0; n < 8; ++n) {
      int gbase = gh * 512 + wv * 128 + n * 16;
      int gcol = gbase + col;
      int q = gcol >> 8;
      const float* Bq = (q == 0) ? bi : (q == 1) ? bf : (q == 2) ? bo : bc;
      float bv = Bq[gcol & 255];
      half8 wf[4];
#pragma unroll
      for (int k = 0; k < 4; ++k)
        wf[k] = *(const half8*)(w16x + (size_t)(gbase + col) * 128 + k * 32 + kq * 8);
      int w2 = (gbase >> 6) & 3;
      int n2 = (gbase >> 8) * 4 + ((gbase >> 4) & 3);
#pragma unroll
      for (int mm = 0; mm < 4; ++mm) {
        f32x4 acc = {bv, bv, bv, bv};
#pragma unroll
        for (int k = 0; k < 4; ++k) acc = MFMA16(afr[mm][k], wf[k], acc);
        int tl = tch * 8 + mh * 4 + mm;
        size_t idx = ((((size_t)tl * 16 + bg) * 4 + w2) * 16 + n2) * 256 + l * 4;
        unsigned int lo = (unsigned int)__half_as_ushort(__float2half_rn(acc[0])) |
                          ((unsigned int)__half_as_ushort(__float2half_rn(acc[1])) << 16);
        unsigned int hi = (unsigned int)__half_as_ushort(__float2half_rn(acc[2])) |
                          ((unsigned int)__half_as_ushort(__float2half_rn(acc[3])) << 16);
        uint2 v = {lo, hi};
        *(uint2*)(gx + idx) = v;
      }
    }
  }
}

// ---------------------------------------------------------------------------
// Phase 2: persistent recurrence, 512 threads, 2 waves/SIMD, 256-VGPR cap.
// Wh frag linear index i = (ctl*4+q)*8+k; i<46 in VGPR, else per-wave LDS.
// ---------------------------------------------------------------------------
#define NFV 46

#define WFRAG(ctl, q, k)                                                      \
  ((((ctl) * 4 + (q)) * 8 + (k)) < NFV                                        \
       ? wfr[(((ctl) * 4 + (q)) * 8 + (k))]                                   \
       : *(const half8*)(WL + ((((ctl) * 4 + (q)) * 8 + (k)) - NFV) * 1024 + lofs))

__global__ __launch_bounds__(512, 2) void rec_kernel(
    const float* __restrict__ Wi, const float* __restrict__ Wf,
    const float* __restrict__ Wo, const float* __restrict__ Wc,
    const __half* __restrict__ gx, float* __restrict__ dout,
    float* __restrict__ c_plain, float* __restrict__ c_state,
    float* __restrict__ h_state, int t0, int tc)
{
  __shared__ char lds[163840];  // 8 waves * 18 KB W frags (144K) + 16 KB HF dbuf
  const int tid = threadIdx.x;
  const int l = tid & 63, w = tid >> 6;
  const int kq = l >> 4, col = l & 15;
  const int lofs = l * 16;
  const int bg = blockIdx.x;
  char* WL = lds + w * 18432;
  char* HF = lds + 147456;

  // ---- load resident Wh fragments (h-part cols [128,384)) ----
  half8 wfr[NFV];
#pragma unroll
  for (int ctl = 0; ctl < 2; ++ctl) {
#pragma unroll
    for (int q = 0; q < 4; ++q) {
      const float* Wq = (q == 0) ? Wi : (q == 1) ? Wf : (q == 2) ? Wo : Wc;
      int j = (w * 2 + ctl) * 16 + col;
      const float* src = Wq + (size_t)j * 384 + 128 + kq * 8;
#pragma unroll
      for (int k = 0; k < 8; ++k) {
        float4 a = *(const float4*)(src + k * 32);
        float4 b = *(const float4*)(src + k * 32 + 4);
        half8 h = {(_Float16)a.x, (_Float16)a.y, (_Float16)a.z, (_Float16)a.w,
                   (_Float16)b.x, (_Float16)b.y, (_Float16)b.z, (_Float16)b.w};
        int i = (ctl * 4 + q) * 8 + k;
        if (i < NFV)
          wfr[i] = h;
        else
          *(half8*)(WL + (i - NFV) * 1024 + lofs) = h;
      }
    }
  }

  // ---- state init / restore (h into HF buf 0) ----
  float cst[8];
  if (t0 == 0) {
#pragma unroll
    for (int i = 0; i < 8; ++i) cst[i] = 0.f;
    uint4 z = {0, 0, 0, 0};
    *(uint4*)(HF + tid * 16) = z;
  } else {
#pragma unroll
    for (int i = 0; i < 8; ++i) cst[i] = c_state[(size_t)(bg * 512 + tid) * 8 + i];
    ((uint4*)HF)[tid] = ((const uint4*)((const char*)h_state + bg * 8192))[tid];
  }

  // ---- Gx prefetch: tile (q,ctl) at gbase + q*2048 + ctl*512 + tt*524288 ----
  const char* gbase = (const char*)gx + (size_t)bg * 32768 + (w >> 1) * 8192 +
                      (w & 1) * 1024 + l * 8;
  uint2 gA[4], gB[4];
#pragma unroll
  for (int q = 0; q < 4; ++q) {
    gA[q] = *(const uint2*)(gbase + q * 2048);
    gB[q] = *(const uint2*)(gbase + q * 2048 + 512);
  }

  for (int tt = 0; tt < tc; ++tt) {
    __syncthreads();  // prev-step writes (to this step's read buf) visible
    const char* rb = HF + ((tt & 1) << 13);
    char* wb = HF + (((tt & 1) ^ 1) << 13);
    const bool last = (t0 + tt == 1023);
    const bool pf = (tt + 1 < tc);
    const char* gn = gbase + (size_t)(tt + 1) * 524288;

#pragma unroll
    for (int ctl = 0; ctl < 2; ++ctl) {
      f32x4 acc[4];
#pragma unroll
      for (int q = 0; q < 4; ++q) {
        uint2 g = ctl ? gB[q] : gA[q];
        float2 p0 = h2f2(g.x), p1 = h2f2(g.y);
        acc[q] = {p0.x, p0.y, p1.x, p1.y};
      }
      if (pf) {  // refill this ctl-group for step tt+1 (hides under MFMA)
#pragma unroll
        for (int q = 0; q < 4; ++q) {
          uint2 v = *(const uint2*)(gn + q * 2048 + ctl * 512);
          if (ctl) gB[q] = v; else gA[q] = v;
        }
      }
#pragma unroll
      for (int kh = 0; kh < 2; ++kh) {
        half8 afr[4];
#pragma unroll
        for (int k2 = 0; k2 < 4; ++k2)
          afr[k2] = *(const half8*)(rb + (kh * 4 + k2) * 1024 + lofs);
#pragma unroll
        for (int k2 = 0; k2 < 4; ++k2) {
          acc[0] = MFMA16(afr[k2], WFRAG(ctl, 0, kh * 4 + k2), acc[0]);
          acc[1] = MFMA16(afr[k2], WFRAG(ctl, 1, kh * 4 + k2), acc[1]);
          acc[2] = MFMA16(afr[k2], WFRAG(ctl, 2, kh * 4 + k2), acc[2]);
          acc[3] = MFMA16(afr[k2], WFRAG(ctl, 3, kh * 4 + k2), acc[3]);
        }
      }
      // ---- activations + h-frag write (to write buf) ----
      char* hwp = wb + w * 1024 + ctl * 512 + ((l >> 3) & 1) * 256 + kq * 64 + (l & 7) * 2;
#pragma unroll
      for (int rg = 0; rg < 4; ++rg) {
        float a_i = acc[0][rg], a_f = acc[1][rg], a_o = acc[2][rg], a_c = acc[3][rg];
        // i*tanh(c~) = (eC-1) / ((1+eA)(eC+1)),  eA=e^-ai, eC=e^{2ac}
        float eA = __expf(-fminf(fmaxf(a_i, -40.f), 40.f));
        float eC = __expf(2.f * fminf(fmaxf(a_c, -15.f), 15.f));
        float ict = (eC - 1.f) * __builtin_amdgcn_rcpf((1.f + eA) * (eC + 1.f));
        float fg = sigf(a_f);
        float cv = fg * cst[ctl * 4 + rg] + ict;
        cst[ctl * 4 + rg] = cv;
        // o*tanh(cv) = (eV-1) / ((1+eO)(eV+1))
        float eO = __expf(-fminf(fmaxf(a_o, -40.f), 40.f));
        float eV = __expf(2.f * fminf(fmaxf(cv, -15.f), 15.f));
        float hv = (eV - 1.f) * __builtin_amdgcn_rcpf((1.f + eO) * (eV + 1.f));
        *(_Float16*)(hwp + rg * 16) = (_Float16)hv;
        if (last) {
          int j = w * 32 + ctl * 16 + col;
          int rrow = bg * 16 + kq * 4 + rg;
          dout[256 + (size_t)rrow * 256 + j] = hv;
          c_plain[(size_t)rrow * 256 + j] = cv;
        }
      }
    }
  }
  __syncthreads();
  // ---- save chunk state (h from buf tc&1) ----
#pragma unroll
  for (int i = 0; i < 8; ++i) c_state[(size_t)(bg * 512 + tid) * 8 + i] = cst[i];
  const char* fb = HF + ((tc & 1) << 13);
  ((uint4*)((char*)h_state + bg * 8192))[tid] = ((const uint4*)fb)[tid];
}

// ---------------------------------------------------------------------------
// Phase 3: out[b] = sigmoid(hid[b,:].W2[:256] + cov[b,:].W2[256:] + b2)
// ---------------------------------------------------------------------------
__global__ void head_kernel(const float* __restrict__ hid, const float* __restrict__ cpl,
                            const float* __restrict__ W2, const float* __restrict__ b2,
                            float* __restrict__ out)
{
  int b = blockIdx.x, l = threadIdx.x;  // 64 threads
  float4 hv = ((const float4*)(hid + (size_t)b * 256))[l];
  float4 wv = ((const float4*)W2)[l];
  float s = hv.x * wv.x + hv.y * wv.y + hv.z * wv.z + hv.w * wv.w;
  float4 cv = ((const float4*)(cpl + (size_t)b * 256))[l];
  float4 wc = ((const float4*)(W2 + 256))[l];
  s += cv.x * wc.x + cv.y * wc.y + cv.z * wc.z + cv.w * wc.w;
#pragma unroll
  for (int off = 32; off > 0; off >>= 1) s += __shfl_down(s, off, 64);
  if (l == 0) out[b] = 1.f / (1.f + __expf(-(s + b2[0])));
}

// ---------------------------------------------------------------------------
extern "C" void kernel_launch(void* const* d_in, const int* in_sizes, int n_in,
                              void* d_out, int out_size, void* d_ws, size_t ws_size,
                              hipStream_t stream)
{
  const float* x  = (const float*)d_in[0];
  const float* Wi = (const float*)d_in[1];
  const float* bi = (const float*)d_in[2];
  const float* Wf = (const float*)d_in[3];
  const float* bf = (const float*)d_in[4];
  const float* Wo = (const float*)d_in[5];
  const float* bo = (const float*)d_in[6];
  const float* Wc = (const float*)d_in[7];
  const float* bc = (const float*)d_in[8];
  const float* W2 = (const float*)d_in[9];
  const float* b2 = (const float*)d_in[10];
  float* out = (float*)d_out;

  // ws layout: [gx: TC*512KB][c_plain 256KB][c_state 256KB][h_state 128KB][w16x 256KB]
  char* ws = (char*)d_ws;
  const size_t state_bytes = (size_t)896 * 1024;
  size_t avail = ws_size > state_bytes ? ws_size - state_bytes : 0;
  size_t tcap = avail / 524288;
  int TC = (int)(tcap > 1024 ? 1024 : (tcap & ~(size_t)7));
  if (TC < 8) TC = 8;  // requires ws_size >= ~5.2 MB
  __half* gxb = (__half*)ws;
  float* c_plain = (float*)(ws + (size_t)TC * 524288);
  float* c_state = c_plain + 65536;
  float* h_state = c_state + 65536;
  __half* w16x = (__half*)(h_state + 32768);

  w16_kernel<<<1024, 128, 0, stream>>>(Wi, Wf, Wo, Wc, w16x);
  for (int t0 = 0; t0 < 1024; t0 += TC) {
    int tcn = (1024 - t0 < TC) ? (1024 - t0) : TC;
    gx_kernel<<<dim3(tcn / 8, 16, 2), 256, 0, stream>>>(w16x, bi, bf, bo, bc, x, gxb, t0);
    rec_kernel<<<16, 512, 0, stream>>>(Wi, Wf, Wo, Wc, gxb, out, c_plain, c_state,
                                       h_state, t0, tcn);
  }
  head_kernel<<<256, 64, 0, stream>>>(out + 256, c_plain, W2, b2, out);
}

// Round 4
// 3977.893 us; speedup vs baseline: 1.6787x; 1.1623x over previous
//
#include <hip/hip_runtime.h>
#include <hip/hip_fp16.h>

// LSTM: B=256, T=1024, D=128, H=256.
// w16_kernel: W x-part (4x[256,384] f32, cols 0..127) -> w16x [1024][128] f16, once.
// gx_kernel : Gx[b,t,g] = x[b,t,:] @ W[:, :128]^T + bias (f16, MFMA, frag-permuted, no LDS).
// rec_kernel: persistent recurrence, 16 wgs x 512 thr, 2 waves/SIMD FORCED via
//             amdgpu_waves_per_eu(2,2) -> 256-VGPR cap (R1-R3 silently spilled at 128).
//             Wh frags: 46/wave in VGPR/AGPR (184 regs), 18/wave in LDS (144 KB);
//             h exchange double-buffered (16 KB). One barrier per step.
//             Gx: 8-reg rolling window, refilled one ctl-phase ahead.
// head_kernel: out[b] = sigmoid([hid, cov] @ W2^T + b2).

typedef _Float16 half8 __attribute__((ext_vector_type(8)));
typedef float f32x4 __attribute__((ext_vector_type(4)));

#define MFMA16(a, b, c) __builtin_amdgcn_mfma_f32_16x16x32_f16((a), (b), (c), 0, 0, 0)

__device__ __forceinline__ float sigf(float x) {
  x = fminf(fmaxf(x, -30.f), 30.f);
  return __builtin_amdgcn_rcpf(1.f + __expf(-x));
}
__device__ __forceinline__ float2 h2f2(unsigned int u) {
  __half2 h;
  __builtin_memcpy(&h, &u, 4);
  return __half22float2(h);
}

// ---------------------------------------------------------------------------
// W x-part -> f16, rows g = q*256 + r, cols 0..127.
// ---------------------------------------------------------------------------
__global__ void w16_kernel(const float* __restrict__ Wi, const float* __restrict__ Wf,
                           const float* __restrict__ Wo, const float* __restrict__ Wc,
                           __half* __restrict__ w16x)
{
  int g = blockIdx.x, c = threadIdx.x;  // 1024 blocks x 128 threads
  int q = g >> 8;
  const float* Wq = (q == 0) ? Wi : (q == 1) ? Wf : (q == 2) ? Wo : Wc;
  w16x[g * 128 + c] = __float2half_rn(Wq[(size_t)(g & 255) * 384 + c]);
}

// ---------------------------------------------------------------------------
// Phase 1: x-part GEMM, no LDS. grid=(TC/8, 16, 2), 256 thr (4 waves).
// Output layout: [tl][bg][w2 4][n2 16][lane 64][reg 4], w2=(g>>6)&3,
//   n2=(g>>8)*4+((g>>4)&3), g = gate*256 + col.  (verified R1-R3)
// ---------------------------------------------------------------------------
__global__ __launch_bounds__(256) void gx_kernel(
    const __half* __restrict__ w16x,
    const float* __restrict__ bi, const float* __restrict__ bf,
    const float* __restrict__ bo, const float* __restrict__ bc,
    const float* __restrict__ x, __half* __restrict__ gx, int t0)
{
  const int tid = threadIdx.x;
  const int l = tid & 63, wv = tid >> 6;
  const int kq = l >> 4, col = l & 15;
  const int tch = blockIdx.x, bg = blockIdx.y, gh = blockIdx.z;
  const size_t brow = (size_t)(bg * 16 + col);

#pragma unroll
  for (int mh = 0; mh < 2; ++mh) {
    half8 afr[4][4];
#pragma unroll
    for (int mm = 0; mm < 4; ++mm) {
      int tt = t0 + tch * 8 + mh * 4 + mm;
      const float* xp = x + (brow * 1024 + tt) * 128 + kq * 8;
#pragma unroll
      for (int k = 0; k < 4; ++k) {
        float4 a = *(const float4*)(xp + k * 32);
        float4 b = *(const float4*)(xp + k * 32 + 4);
        afr[mm][k] = {(_Float16)a.x, (_Float16)a.y, (_Float16)a.z, (_Float16)a.w,
                      (_Float16)b.x, (_Float16)b.y, (_Float16)b.z, (_Float16)b.w};
      }
    }
#pragma unroll
    for (int n = 0; n < 8; ++n) {
      int gbase = gh * 512 + wv * 128 + n * 16;
      int gcol = gbase + col;
      int q = gcol >> 8;
      const float* Bq = (q == 0) ? bi : (q == 1) ? bf : (q == 2) ? bo : bc;
      float bv = Bq[gcol & 255];
      half8 wf[4];
#pragma unroll
      for (int k = 0; k < 4; ++k)
        wf[k] = *(const half8*)(w16x + (size_t)(gbase + col) * 128 + k * 32 + kq * 8);
      int w2 = (gbase >> 6) & 3;
      int n2 = (gbase >> 8) * 4 + ((gbase >> 4) & 3);
#pragma unroll
      for (int mm = 0; mm < 4; ++mm) {
        f32x4 acc = {bv, bv, bv, bv};
#pragma unroll
        for (int k = 0; k < 4; ++k) acc = MFMA16(afr[mm][k], wf[k], acc);
        int tl = tch * 8 + mh * 4 + mm;
        size_t idx = ((((size_t)tl * 16 + bg) * 4 + w2) * 16 + n2) * 256 + l * 4;
        unsigned int lo = (unsigned int)__half_as_ushort(__float2half_rn(acc[0])) |
                          ((unsigned int)__half_as_ushort(__float2half_rn(acc[1])) << 16);
        unsigned int hi = (unsigned int)__half_as_ushort(__float2half_rn(acc[2])) |
                          ((unsigned int)__half_as_ushort(__float2half_rn(acc[3])) << 16);
        uint2 v = {lo, hi};
        *(uint2*)(gx + idx) = v;
      }
    }
  }
}

// ---------------------------------------------------------------------------
// Phase 2: persistent recurrence, 512 threads, FORCED 2 waves/SIMD (256 regs).
// Wh frag linear index i = (ctl*4+q)*8+k; i<46 in VGPR, else per-wave LDS.
// ---------------------------------------------------------------------------
#define NFV 46

#define WFRAG(ctl, q, k)                                                      \
  ((((ctl) * 4 + (q)) * 8 + (k)) < NFV                                        \
       ? wfr[(((ctl) * 4 + (q)) * 8 + (k))]                                   \
       : *(const half8*)(WL + ((((ctl) * 4 + (q)) * 8 + (k)) - NFV) * 1024 + lofs))

__global__ __launch_bounds__(512) __attribute__((amdgpu_waves_per_eu(2, 2)))
void rec_kernel(
    const float* __restrict__ Wi, const float* __restrict__ Wf,
    const float* __restrict__ Wo, const float* __restrict__ Wc,
    const __half* __restrict__ gx, float* __restrict__ dout,
    float* __restrict__ c_plain, float* __restrict__ c_state,
    float* __restrict__ h_state, int t0, int tc)
{
  __shared__ char lds[163840];  // 8 waves * 18 KB W frags (144K) + 16 KB HF dbuf
  const int tid = threadIdx.x;
  const int l = tid & 63, w = tid >> 6;
  const int kq = l >> 4, col = l & 15;
  const int lofs = l * 16;
  const int bg = blockIdx.x;
  char* WL = lds + w * 18432;
  char* HF = lds + 147456;

  // ---- load resident Wh fragments (h-part cols [128,384)) ----
  half8 wfr[NFV];
#pragma unroll
  for (int ctl = 0; ctl < 2; ++ctl) {
#pragma unroll
    for (int q = 0; q < 4; ++q) {
      const float* Wq = (q == 0) ? Wi : (q == 1) ? Wf : (q == 2) ? Wo : Wc;
      int j = (w * 2 + ctl) * 16 + col;
      const float* src = Wq + (size_t)j * 384 + 128 + kq * 8;
#pragma unroll
      for (int k = 0; k < 8; ++k) {
        float4 a = *(const float4*)(src + k * 32);
        float4 b = *(const float4*)(src + k * 32 + 4);
        half8 h = {(_Float16)a.x, (_Float16)a.y, (_Float16)a.z, (_Float16)a.w,
                   (_Float16)b.x, (_Float16)b.y, (_Float16)b.z, (_Float16)b.w};
        int i = (ctl * 4 + q) * 8 + k;
        if (i < NFV)
          wfr[i] = h;
        else
          *(half8*)(WL + (i - NFV) * 1024 + lofs) = h;
      }
    }
  }

  // ---- state init / restore (h into HF buf 0) ----
  float cst[8];
  if (t0 == 0) {
#pragma unroll
    for (int i = 0; i < 8; ++i) cst[i] = 0.f;
    uint4 z = {0, 0, 0, 0};
    *(uint4*)(HF + tid * 16) = z;
  } else {
#pragma unroll
    for (int i = 0; i < 8; ++i) cst[i] = c_state[(size_t)(bg * 512 + tid) * 8 + i];
    ((uint4*)HF)[tid] = ((const uint4*)((const char*)h_state + bg * 8192))[tid];
  }

  // ---- Gx rolling window: tile (q,ctl) at gbase + q*2048 + ctl*512 + tt*524288 ----
  const char* gbase = (const char*)gx + (size_t)bg * 32768 + (w >> 1) * 8192 +
                      (w & 1) * 1024 + l * 8;
  uint2 gcur[4];
#pragma unroll
  for (int q = 0; q < 4; ++q) gcur[q] = *(const uint2*)(gbase + q * 2048);
  const char* gstep = gbase;

  for (int tt = 0; tt < tc; ++tt) {
    __syncthreads();  // prev-step writes (to this step's read buf) visible
    const char* rb = HF + ((tt & 1) << 13);
    char* wb = HF + (((tt & 1) ^ 1) << 13);
    const bool last = (t0 + tt == 1023);
    const bool pf = (tt + 1 < tc);

#pragma unroll
    for (int ctl = 0; ctl < 2; ++ctl) {
      f32x4 acc[4];
#pragma unroll
      for (int q = 0; q < 4; ++q) {
        float2 p0 = h2f2(gcur[q].x), p1 = h2f2(gcur[q].y);
        acc[q] = {p0.x, p0.y, p1.x, p1.y};
      }
      // refill window one ctl-phase ahead (latency hides under MFMA+VALU)
      if (ctl == 0) {
#pragma unroll
        for (int q = 0; q < 4; ++q)
          gcur[q] = *(const uint2*)(gstep + q * 2048 + 512);
      } else if (pf) {
#pragma unroll
        for (int q = 0; q < 4; ++q)
          gcur[q] = *(const uint2*)(gstep + 524288 + q * 2048);
      }
#pragma unroll
      for (int kh = 0; kh < 2; ++kh) {
        half8 afr[4];
#pragma unroll
        for (int k2 = 0; k2 < 4; ++k2)
          afr[k2] = *(const half8*)(rb + (kh * 4 + k2) * 1024 + lofs);
#pragma unroll
        for (int k2 = 0; k2 < 4; ++k2) {
          acc[0] = MFMA16(afr[k2], WFRAG(ctl, 0, kh * 4 + k2), acc[0]);
          acc[1] = MFMA16(afr[k2], WFRAG(ctl, 1, kh * 4 + k2), acc[1]);
          acc[2] = MFMA16(afr[k2], WFRAG(ctl, 2, kh * 4 + k2), acc[2]);
          acc[3] = MFMA16(afr[k2], WFRAG(ctl, 3, kh * 4 + k2), acc[3]);
        }
      }
      // ---- activations + h-frag write (to write buf) ----
      char* hwp = wb + w * 1024 + ctl * 512 + ((l >> 3) & 1) * 256 + kq * 64 + (l & 7) * 2;
#pragma unroll
      for (int rg = 0; rg < 4; ++rg) {
        float a_i = acc[0][rg], a_f = acc[1][rg], a_o = acc[2][rg], a_c = acc[3][rg];
        // i*tanh(c~) = (eC-1) / ((1+eA)(eC+1)),  eA=e^-ai, eC=e^{2ac}
        float eA = __expf(-fminf(fmaxf(a_i, -40.f), 40.f));
        float eC = __expf(2.f * fminf(fmaxf(a_c, -15.f), 15.f));
        float ict = (eC - 1.f) * __builtin_amdgcn_rcpf((1.f + eA) * (eC + 1.f));
        float fg = sigf(a_f);
        float cv = fg * cst[ctl * 4 + rg] + ict;
        cst[ctl * 4 + rg] = cv;
        // o*tanh(cv) = (eV-1) / ((1+eO)(eV+1))
        float eO = __expf(-fminf(fmaxf(a_o, -40.f), 40.f));
        float eV = __expf(2.f * fminf(fmaxf(cv, -15.f), 15.f));
        float hv = (eV - 1.f) * __builtin_amdgcn_rcpf((1.f + eO) * (eV + 1.f));
        *(_Float16*)(hwp + rg * 16) = (_Float16)hv;
        if (last) {
          int j = w * 32 + ctl * 16 + col;
          int rrow = bg * 16 + kq * 4 + rg;
          dout[256 + (size_t)rrow * 256 + j] = hv;
          c_plain[(size_t)rrow * 256 + j] = cv;
        }
      }
    }
    gstep += 524288;
  }
  __syncthreads();
  // ---- save chunk state (h from buf tc&1) ----
#pragma unroll
  for (int i = 0; i < 8; ++i) c_state[(size_t)(bg * 512 + tid) * 8 + i] = cst[i];
  const char* fb = HF + ((tc & 1) << 13);
  ((uint4*)((char*)h_state + bg * 8192))[tid] = ((const uint4*)fb)[tid];
}

// ---------------------------------------------------------------------------
// Phase 3: out[b] = sigmoid(hid[b,:].W2[:256] + cov[b,:].W2[256:] + b2)
// ---------------------------------------------------------------------------
__global__ void head_kernel(const float* __restrict__ hid, const float* __restrict__ cpl,
                            const float* __restrict__ W2, const float* __restrict__ b2,
                            float* __restrict__ out)
{
  int b = blockIdx.x, l = threadIdx.x;  // 64 threads
  float4 hv = ((const float4*)(hid + (size_t)b * 256))[l];
  float4 wv = ((const float4*)W2)[l];
  float s = hv.x * wv.x + hv.y * wv.y + hv.z * wv.z + hv.w * wv.w;
  float4 cv = ((const float4*)(cpl + (size_t)b * 256))[l];
  float4 wc = ((const float4*)(W2 + 256))[l];
  s += cv.x * wc.x + cv.y * wc.y + cv.z * wc.z + cv.w * wc.w;
#pragma unroll
  for (int off = 32; off > 0; off >>= 1) s += __shfl_down(s, off, 64);
  if (l == 0) out[b] = 1.f / (1.f + __expf(-(s + b2[0])));
}

// ---------------------------------------------------------------------------
extern "C" void kernel_launch(void* const* d_in, const int* in_sizes, int n_in,
                              void* d_out, int out_size, void* d_ws, size_t ws_size,
                              hipStream_t stream)
{
  const float* x  = (const float*)d_in[0];
  const float* Wi = (const float*)d_in[1];
  const float* bi = (const float*)d_in[2];
  const float* Wf = (const float*)d_in[3];
  const float* bf = (const float*)d_in[4];
  const float* Wo = (const float*)d_in[5];
  const float* bo = (const float*)d_in[6];
  const float* Wc = (const float*)d_in[7];
  const float* bc = (const float*)d_in[8];
  const float* W2 = (const float*)d_in[9];
  const float* b2 = (const float*)d_in[10];
  float* out = (float*)d_out;

  // ws layout: [gx: TC*512KB][c_plain 256KB][c_state 256KB][h_state 128KB][w16x 256KB]
  char* ws = (char*)d_ws;
  const size_t state_bytes = (size_t)896 * 1024;
  size_t avail = ws_size > state_bytes ? ws_size - state_bytes : 0;
  size_t tcap = avail / 524288;
  int TC = (int)(tcap > 1024 ? 1024 : (tcap & ~(size_t)7));
  if (TC < 8) TC = 8;  // requires ws_size >= ~5.2 MB
  __half* gxb = (__half*)ws;
  float* c_plain = (float*)(ws + (size_t)TC * 524288);
  float* c_state = c_plain + 65536;
  float* h_state = c_state + 65536;
  __half* w16x = (__half*)(h_state + 32768);

  w16_kernel<<<1024, 128, 0, stream>>>(Wi, Wf, Wo, Wc, w16x);
  for (int t0 = 0; t0 < 1024; t0 += TC) {
    int tcn = (1024 - t0 < TC) ? (1024 - t0) : TC;
    gx_kernel<<<dim3(tcn / 8, 16, 2), 256, 0, stream>>>(w16x, bi, bf, bo, bc, x, gxb, t0);
    rec_kernel<<<16, 512, 0, stream>>>(Wi, Wf, Wo, Wc, gxb, out, c_plain, c_state,
                                       h_state, t0, tcn);
  }
  head_kernel<<<256, 64, 0, stream>>>(out + 256, c_plain, W2, b2, out);
}